// Round 10
// baseline (467.690 us; speedup 1.0000x reference)
//
#include <hip/hip_runtime.h>

typedef unsigned short ushort_t;
typedef unsigned int uint_t;

using short8 = __attribute__((ext_vector_type(8))) short;
using f32x4  = __attribute__((ext_vector_type(4))) float;

#define N_BATCH   64
#define C_MID     256
#define H_OUT     28
#define W_OUT     28
#define SPATIAL   (H_OUT*W_OUT)
#define OUT_ELEMS (N_BATCH*C_MID*SPATIAL)   // 12,845,056

// histogram: 2048 bins over [-16,16), width 1/64
#define NBINS 2048
#define BIN_LO (-16.0f)
#define BIN_INV 64.0f
#define BIN_W  0.015625f

// padded channels-last geometry (u16 element units)
#define XT_ROW   (57*128)        // 7296
#define XT_IMG   (57*57*128)     // 415872
#define O1_ROW   (30*256)        // 7680
#define O1_IMG   (30*30*256)     // 230400

// counted waits + raw barrier (memory clobber pins LDS reads/writes ordering)
#define WAITVM(n) asm volatile("s_waitcnt vmcnt(" #n ")" ::: "memory")
#define BARRIER() asm volatile("s_barrier" ::: "memory")

__device__ __forceinline__ ushort_t f2bf(float f) {
    uint_t u = __float_as_uint(f);
    u += 0x7FFFu + ((u >> 16) & 1u);
    return (ushort_t)(u >> 16);
}

__device__ __forceinline__ void gll16(const ushort_t* g, void* l) {
    __builtin_amdgcn_global_load_lds(
        (const __attribute__((address_space(1))) unsigned int*)g,
        (__attribute__((address_space(3))) unsigned int*)l, 16, 0, 0);
}

// ---------------------------------------------------------------------------
// Last-block percentile fold: hist = this block's LDS hist area (>=NBINS+256
// uints usable), hf = global histogram, cnt = election counter, outp = 99
// floats. Each block: flush own hist -> fence -> elect; last block rebuilds
// hf in LDS (device-scope atomic loads), 256-seg scan, walk, write.
// ---------------------------------------------------------------------------
__device__ __forceinline__ void hist_fold(
    uint_t* hist, uint_t* hf, uint_t* cnt, float* outp,
    int tid, uint_t nblk)
{
    __syncthreads();
    for (int i = tid; i < NBINS; i += 256) {
        uint_t v = hist[i];
        if (v) atomicAdd(&hf[i], v);
    }
    __threadfence();
    __syncthreads();
    __shared__ uint_t last_;
    if (tid == 0) last_ = (atomicAdd(cnt, 1u) == nblk - 1u) ? 1u : 0u;
    __syncthreads();
    if (!last_) return;

    uint_t* cs = hist + NBINS;           // 256 scan slots
    for (int i = tid; i < NBINS; i += 256) hist[i] = atomicAdd(&hf[i], 0u);
    __syncthreads();
    uint_t s = 0;
    #pragma unroll
    for (int j = 0; j < 8; ++j) s += hist[tid * 8 + j];
    cs[tid] = s;
    __syncthreads();
    for (int d = 1; d < 256; d <<= 1) {
        uint_t v = (tid >= d) ? cs[tid - d] : 0;
        __syncthreads();
        cs[tid] += v;
        __syncthreads();
    }
    if (tid >= 1 && tid <= 99) {
        long long k = 1 + (long long)llrint(0.01 * (double)tid * (double)(OUT_ELEMS - 1));
        int lo = 0, hi = 255;
        while (lo < hi) { int mid = (lo + hi) >> 1; if ((long long)cs[mid] < k) lo = mid + 1; else hi = mid; }
        long long cum = (lo == 0) ? 0 : (long long)cs[lo - 1];
        int b = lo * 8;
        while (cum + (long long)hist[b] < k) { cum += hist[b]; ++b; }
        outp[tid - 1] = BIN_LO + ((float)b + 0.5f) * BIN_W;
    }
}

// ---------------------------------------------------------------------------
// prep: merged zwtrans + xtrans (5 -> 3 dispatches total).
//   bxx <  87 : zero borders of xT/o1T
//   87..124   : weight transform + zero hf/cnt
//   125..138  : xtrans (NCHW f32 -> padded channels-last bf16), g = bxx-125
// ---------------------------------------------------------------------------
__global__ __launch_bounds__(256) void prep(
    uint_t* __restrict__ xT32, uint_t* __restrict__ o1T32,
    const float* __restrict__ x, const float* __restrict__ w1,
    const float* __restrict__ w2, const float* __restrict__ wid,
    ushort_t* __restrict__ wT1, ushort_t* __restrict__ wT2,
    uint_t* __restrict__ hfA, uint_t* __restrict__ hfB,
    uint_t* __restrict__ cnt, ushort_t* __restrict__ xT)
{
    __shared__ ushort_t t[224 * 130];
    const int bxx = blockIdx.x, y = blockIdx.y, tid = threadIdx.x;
    if (bxx < 87) {
        int i = bxx * 256 + tid;
        int n = y;
        if (i >= 22080) return;
        if (i < 7232) {
            uint_t* base = xT32 + (size_t)n * (XT_IMG / 2);
            if (i < 3648) base[i] = 0;                              // row 0
            else { int j = i - 3648; int r = (j >> 6) + 1;          // col 0
                   base[r * (XT_ROW / 2) + (j & 63)] = 0; }
        } else {
            int k = i - 7232;
            uint_t* base = o1T32 + (size_t)n * (O1_IMG / 2);
            if (k < 3840) base[k] = 0;                              // row 0
            else if (k < 7680) base[29 * (O1_ROW / 2) + (k - 3840)] = 0;
            else if (k < 11264) { int j = k - 7680; int r = (j >> 7) + 1;
                   base[r * (O1_ROW / 2) + (j & 127)] = 0; }        // col 0
            else { int j = k - 11264; int r = (j >> 7) + 1;
                   base[r * (O1_ROW / 2) + 29 * 128 + (j & 127)] = 0; }
        }
    } else if (bxx < 125) {
        int idx = ((bxx - 87) * 64 + y) * 256 + tid;   // 0..622591
        if (idx < 2)         cnt[idx] = 0;
        if (idx < 2048)      hfA[idx] = 0;
        else if (idx < 4096) hfB[idx - 2048] = 0;
        if (idx < 256 * 1152) {
            int co = idx / 1152, k = idx % 1152;
            int g = k >> 7, ci = k & 127;
            wT1[idx] = f2bf(w1[(co * 128 + ci) * 9 + g]);
        }
        if (idx < 256 * 2432) {
            int co = idx / 2432, k = idx % 2432;
            float v;
            if (k < 2304) { int g = k >> 8, ci = k & 255; v = w2[(co * 256 + ci) * 9 + g]; }
            else          { v = wid[co * 128 + (k - 2304)]; }
            wT2[idx] = f2bf(v);
        }
    } else {
        const int g = bxx - 125, n = y;
        const float* xs = x + ((size_t)n * 128) * 3136 + g * 4 * 56;
        #pragma unroll
        for (int it = 0; it < 28; ++it) {
            int f = it * 256 + tid;      // 7168 = 128 ci x 56 float4
            int ci = f / 56, r4 = f % 56;
            float4 v = *(const float4*)(xs + ci * 3136 + r4 * 4);
            t[(r4 * 4 + 0) * 130 + ci] = f2bf(v.x);
            t[(r4 * 4 + 1) * 130 + ci] = f2bf(v.y);
            t[(r4 * 4 + 2) * 130 + ci] = f2bf(v.z);
            t[(r4 * 4 + 3) * 130 + ci] = f2bf(v.w);
        }
        __syncthreads();
        ushort_t* xo = xT + (size_t)n * XT_IMG + (g * 4 + 1) * XT_ROW + 128;
        for (int it = 0; it < 56; ++it) {
            int f = it * 256 + tid;
            int pos = f >> 6, c2 = f & 63;
            int r = pos / 56, iw = pos % 56;
            uint_t v = *(const uint_t*)&t[pos * 130 + c2 * 2];
            *(uint_t*)(xo + r * XT_ROW + iw * 128 + c2 * 2) = v;
        }
    }
}

// ---------------------------------------------------------------------------
// conv1 (R1/R5 inner loop, best measured). A staging wave-private (counted
// vmcnt, no per-tap barrier); 2 barriers per ci-chunk for the shared B
// patch. Epilogue: LDS hist -> hf + last-block percentile fold.
// ---------------------------------------------------------------------------
__global__ __launch_bounds__(256, 2) void conv1_mfma(
    const ushort_t* __restrict__ xT, const ushort_t* __restrict__ wT1,
    ushort_t* __restrict__ o1T, uint_t* __restrict__ hf,
    uint_t* __restrict__ cnt, float* __restrict__ outp)
{
    const int bx = blockIdx.x;           // n*7 + rg
    const int tid = threadIdx.x;
    const int wv = tid >> 6, lane = tid & 63;
    const int ln = lane & 15, quad = lane >> 4;
    const int n = bx / 7, rg = bx % 7, r0 = rg * 4;

    __shared__ short8 Ald[2 * 1024];     // 32 KB  [buf][k8 4][co 256]
    __shared__ short8 Bp[2304];          // 36 KB  [k8 4][dr 9][j 57] (513/plane)

    f32x4 acc[4][7];
    #pragma unroll
    for (int a = 0; a < 4; ++a)
        #pragma unroll
        for (int b = 0; b < 7; ++b) acc[a][b] = (f32x4){0.f, 0.f, 0.f, 0.f};

    int drb[7], cl0[7];
    #pragma unroll
    for (int b = 0; b < 7; ++b) {
        int p = b * 16 + ln;
        drb[b] = 2 * (p / 28);           // + kh at use
        cl0[b] = p % 28;
    }

    uint_t poff[9];
    #pragma unroll
    for (int i = 0; i < 9; ++i) {
        int slot = (i * 4 + wv) * 64 + lane;
        int s2 = min(slot, 2051);
        int k8 = s2 / 513;
        int rem = s2 - k8 * 513;
        int dr = rem / 57, j = rem - dr * 57;
        int col = (j < 29) ? (2 * j) : (2 * (j - 29) + 1);
        poff[i] = (uint_t)((2 * r0 + dr) * XT_ROW + col * 128 + k8 * 8);
    }
    const uint_t aoff = (uint_t)((wv * 64 + lane) * 1152);

    const ushort_t* xTimg = xT + (size_t)n * XT_IMG;

    auto stageA = [&](int tap, int c, int buf) {
        #pragma unroll
        for (int jj = 0; jj < 4; ++jj)
            gll16(wT1 + aoff + jj * 8 + tap * 128 + c * 32,
                  (char*)Ald + buf * 16384 + (jj * 256 + wv * 64) * 16);
    };

    for (int c = 0; c < 4; ++c) {
        BARRIER();                       // all waves done reading Bp (prev chunk)
        #pragma unroll
        for (int i = 0; i < 9; ++i)
            gll16(xTimg + poff[i] + c * 32, (char*)Bp + ((i * 4 + wv) * 64) * 16);
        if (c == 0) stageA(0, 0, 0);
        WAITVM(0);                       // own B (+pending A) arrived
        BARRIER();                       // everyone's B arrived

        #pragma unroll
        for (int t = 0; t < 9; ++t) {
            const int st = c * 9 + t;
            const int buf = st & 1;
            if (t < 8)      stageA(t + 1, c, buf ^ 1);
            else if (c < 3) stageA(0, c + 1, buf ^ 1);
            if (c == 3 && t == 8) { WAITVM(0); } else { WAITVM(4); }
            const int kh = t / 3, kw = t - kh * 3;
            short8 af[4], bf[7];
            #pragma unroll
            for (int a = 0; a < 4; ++a)
                af[a] = Ald[buf * 1024 + quad * 256 + wv * 64 + a * 16 + ln];
            #pragma unroll
            for (int b = 0; b < 7; ++b) {
                int dr = drb[b] + kh;
                int j = (kw == 1) ? (29 + cl0[b]) : (cl0[b] + (kw >> 1));
                bf[b] = Bp[quad * 513 + dr * 57 + j];
            }
            __builtin_amdgcn_s_setprio(1);
            #pragma unroll
            for (int a = 0; a < 4; ++a)
                #pragma unroll
                for (int b = 0; b < 7; ++b)
                    acc[a][b] = __builtin_amdgcn_mfma_f32_16x16x32_bf16(
                        af[a], bf[b], acc[a][b], 0, 0, 0);
            __builtin_amdgcn_s_setprio(0);
        }
    }

    // epilogue: hist overlaid on Ald; clamp -> bf16 o1T (padded channels-last)
    __syncthreads();
    uint_t* hist = (uint_t*)Ald;
    for (int i = tid; i < NBINS; i += 256) hist[i] = 0;
    __syncthreads();

    ushort_t* oimg = o1T + (size_t)n * O1_IMG;
    #pragma unroll
    for (int a = 0; a < 4; ++a) {
        int co = wv * 64 + a * 16 + quad * 4;
        #pragma unroll
        for (int b = 0; b < 7; ++b) {
            int p = b * 16 + ln;
            int h = r0 + p / 28, w = p % 28;
            ushort_t pk[4];
            #pragma unroll
            for (int r = 0; r < 4; ++r) {
                float v = acc[a][b][r];
                int bin = (int)((v - BIN_LO) * BIN_INV);
                bin = min(max(bin, 0), NBINS - 1);
                atomicAdd(&hist[bin], 1u);
                pk[r] = f2bf(fminf(fmaxf(v, 0.f), 1.f));
            }
            uint2 u; u.x = (uint_t)pk[0] | ((uint_t)pk[1] << 16);
            u.y = (uint_t)pk[2] | ((uint_t)pk[3] << 16);
            *(uint2*)(oimg + ((h + 1) * 30 + (w + 1)) * 256 + co) = u;
        }
    }

    hist_fold(hist, hf, cnt, outp, tid, 448u);
}

// ---------------------------------------------------------------------------
// conv2 + fused identity (R9 tap-paired pipeline, equal-best measured).
// Epilogue: LDS hist -> hf + last-block percentile fold.
// ---------------------------------------------------------------------------
__global__ __launch_bounds__(256, 2) void conv2_mfma(
    const ushort_t* __restrict__ o1T, const ushort_t* __restrict__ xT,
    const ushort_t* __restrict__ wT2, float* __restrict__ fout,
    uint_t* __restrict__ hf, uint_t* __restrict__ cnt,
    float* __restrict__ outp)
{
    const int bx = blockIdx.x;           // n*4 + rg
    const int by = blockIdx.y;
    const int tid = threadIdx.x;
    const int wv = tid >> 6, lane = tid & 63;
    const int ln = lane & 15, quad = lane >> 4;
    const int n = bx >> 2, rg = bx & 3, r0 = rg * 8;
    const int coh = wv & 1;
    const int pt  = wv >> 1;

    __shared__ short8 Ad[4 * 512];       // 32 KB [slot 4][k8 4][co 128]
    __shared__ short8 Bp[2 * 1280];      // 40 KB [buf 2][ci8 4][dr 10][col 32]

    f32x4 acc[4][7];
    #pragma unroll
    for (int a = 0; a < 4; ++a)
        #pragma unroll
        for (int b = 0; b < 7; ++b) acc[a][b] = (f32x4){0.f, 0.f, 0.f, 0.f};

    int prb[7], cl0[7], hlog[7];
    #pragma unroll
    for (int b = 0; b < 7; ++b) {
        int p = b * 16 + ln;
        int h = r0 + pt * 4 + p / 28;
        hlog[b] = h;
        prb[b] = (min(h, 27) - r0) * 32;
        cl0[b] = p % 28;
    }

    uint_t po[5];
    #pragma unroll
    for (int jj = 0; jj < 5; ++jj) {
        int f = (wv * 5 + jj) * 64 + lane;
        int ci8 = f / 320, rem = f % 320;
        int dr = rem >> 5, cl = rem & 31;
        po[jj] = (uint_t)(min(r0 + dr, 29) * O1_ROW + cl * 256 + ci8 * 8);
    }
    uint_t io[4];
    #pragma unroll
    for (int jj = 0; jj < 4; ++jj) {
        int i2 = min(wv * 4 + jj, 13);
        int slot = i2 * 64 + lane;
        int ci8 = slot / 224, pos = slot % 224;
        int h = min(r0 + pos / 28, 27), w = pos % 28;
        io[jj] = (uint_t)(((2 * h + 1) * 57 + (2 * w + 1)) * 128 + ci8 * 8);
    }

    const ushort_t* o1img = o1T + (size_t)n * O1_IMG;
    const ushort_t* xTimg = xT + (size_t)n * XT_IMG;
    const ushort_t* Ab0 = wT2 + (size_t)(by * 128 + lane) * 2432 + wv * 8;
    const ushort_t* Ab1 = Ab0 + (size_t)64 * 2432;

    auto stageA = [&](int k0, int slot) {          // 2 insts/wave = 8 KB/slot
        gll16(Ab0 + k0, (char*)Ad + slot * 8192 + wv * 2048);
        gll16(Ab1 + k0, (char*)Ad + slot * 8192 + wv * 2048 + 1024);
    };
    auto stageB = [&](int hb, int coff) {          // 5 insts/wave = 20 KB total
        #pragma unroll
        for (int jj = 0; jj < 5; ++jj)
            gll16(o1img + po[jj] + coff, (char*)Bp + hb * 20480 + (wv * 5 + jj) * 1024);
    };
    auto stageI = [&](int ib, int idh) {           // 4 insts/wave
        #pragma unroll
        for (int jj = 0; jj < 4; ++jj) {
            int i2 = min(wv * 4 + jj, 13);
            gll16(xTimg + io[jj] + idh * 32, (char*)Bp + ib * 20480 + i2 * 1024);
        }
    };

    // one tap's compute: af from A slot SL, bf from B buf HD at tap T
#define STEP_MFMA(SL, HD, T) do {                                             \
    const int kh_ = (T) / 3, kw_ = (T) % 3;                                   \
    short8 af_[4], bf_[7];                                                    \
    _Pragma("unroll")                                                         \
    for (int a_ = 0; a_ < 4; ++a_)                                            \
        af_[a_] = Ad[(SL) * 512 + quad * 128 + coh * 64 + a_ * 16 + ln];      \
    _Pragma("unroll")                                                         \
    for (int b_ = 0; b_ < 7; ++b_)                                            \
        bf_[b_] = Bp[(HD) * 1280 + quad * 320 + prb[b_] +                     \
                     kh_ * 32 + cl0[b_] + kw_];                               \
    __builtin_amdgcn_s_setprio(1);                                            \
    _Pragma("unroll")                                                         \
    for (int a_ = 0; a_ < 4; ++a_)                                            \
        _Pragma("unroll")                                                     \
        for (int b_ = 0; b_ < 7; ++b_)                                        \
            acc[a_][b_] = __builtin_amdgcn_mfma_f32_16x16x32_bf16(            \
                af_[a_], bf_[b_], acc[a_][b_], 0, 0, 0);                      \
    __builtin_amdgcn_s_setprio(0);                                            \
} while (0)

// one pair: steps s0 = hh*18 + 2Q, s0+1. All staging post-barrier.
#define PAIR(Q) do {                                                          \
    const int c0 = 2 * (Q), c1 = c0 + 1;                                      \
    const int t0_ = c0 % 9, t1_ = c1 % 9;                                     \
    const int hd0 = c0 / 9, hd1 = c1 / 9;                                     \
    WAITVM(0);                                                                \
    BARRIER();                                                                \
    {   /* stage A for steps s0+2, s0+3 */                                    \
        const int u0 = c0 + 2, u1 = c0 + 3;                                   \
        int k0_, k1_;                                                         \
        if (u0 < 18) k0_ = (u0 % 9) * 256 + (hh * 2 + u0 / 9) * 32;           \
        else k0_ = lastsup ? 2304                                             \
                           : ((u0 - 18) % 9) * 256 + (hh * 2 + 2) * 32;       \
        if (u1 < 18) k1_ = (u1 % 9) * 256 + (hh * 2 + u1 / 9) * 32;           \
        else k1_ = lastsup ? (2304 + (u1 - 18) * 32)                          \
                           : ((u1 - 18) % 9) * 256 + (hh * 2 + 2) * 32;       \
        stageA(k0_, (hh * 18 + u0) & 3);                                      \
        stageA(k1_, (hh * 18 + u1) & 3);                                      \
    }                                                                         \
    if ((Q) == 0) {                       /* t(s1)==1, h = 2hh   */           \
        stageB(1, (hh * 2 + 1) * 32);                                         \
    } else if ((Q) == 5) {                /* t(s0)==1, h = 2hh+1 */           \
        if (!lastsup) stageB(0, (hh * 2 + 2) * 32);                           \
        else          stageI(0, 0);                                           \
    }                                                                         \
    STEP_MFMA((hh * 18 + c0) & 3, hd0, t0_);                                  \
    STEP_MFMA((hh * 18 + c1) & 3, hd1, t1_);                                  \
} while (0)

    // prologue: A(0), A(1), B(chunk 0); retired+published by pair 0
    stageA(0, 0);
    stageA(256, 1);
    stageB(0, 0);

    for (int hh = 0; hh < 4; ++hh) {     // 2 chunks (18 steps, 9 pairs) each
        const bool lastsup = (hh == 3);
        PAIR(0); PAIR(1); PAIR(2); PAIR(3); PAIR(4);
        PAIR(5); PAIR(6); PAIR(7); PAIR(8);
    }
#undef PAIR

    // identity: 4 singleton steps (lead-1 pattern). Step 72+idh: A slot
    // idh (A72,A73 staged at main pair 35; A74,A75 staged at idh 0,1).
    #pragma unroll
    for (int idh = 0; idh < 4; ++idh) {
        WAITVM(0);
        BARRIER();
        if (idh < 2) stageA(2304 + (idh + 2) * 32, idh + 2);
        if (idh < 3) stageI((idh + 1) & 1, idh + 1);
        short8 af[4], bf[7];
        #pragma unroll
        for (int a = 0; a < 4; ++a)
            af[a] = Ad[idh * 512 + quad * 128 + coh * 64 + a * 16 + ln];
        #pragma unroll
        for (int b = 0; b < 7; ++b)
            bf[b] = Bp[(idh & 1) * 1280 + quad * 224 + pt * 112 + b * 16 + ln];
        __builtin_amdgcn_s_setprio(1);
        #pragma unroll
        for (int a = 0; a < 4; ++a)
            #pragma unroll
            for (int b = 0; b < 7; ++b)
                acc[a][b] = __builtin_amdgcn_mfma_f32_16x16x32_bf16(
                    af[a], bf[b], acc[a][b], 0, 0, 0);
        __builtin_amdgcn_s_setprio(0);
    }
#undef STEP_MFMA

    // epilogue: hist overlaid on Ad; clamp -> f32 out (NCHW)
    __syncthreads();
    uint_t* hist = (uint_t*)Ad;
    for (int i = tid; i < NBINS; i += 256) hist[i] = 0;
    __syncthreads();

    #pragma unroll
    for (int a = 0; a < 4; ++a) {
        int co = by * 128 + coh * 64 + a * 16 + quad * 4;
        #pragma unroll
        for (int b = 0; b < 7; ++b) {
            if (hlog[b] <= 27) {
                #pragma unroll
                for (int r = 0; r < 4; ++r) {
                    float v = acc[a][b][r];
                    int bin = (int)((v - BIN_LO) * BIN_INV);
                    bin = min(max(bin, 0), NBINS - 1);
                    atomicAdd(&hist[bin], 1u);
                    fout[((size_t)(n * 256 + co + r)) * SPATIAL +
                         hlog[b] * 28 + cl0[b]] = fminf(fmaxf(v, 0.f), 1.f);
                }
            }
        }
    }

    hist_fold(hist, hf, cnt, outp, tid, 512u);
}

// ---------------------------------------------------------------------------
extern "C" void kernel_launch(void* const* d_in, const int* in_sizes, int n_in,
                              void* d_out, int out_size, void* d_ws, size_t ws_size,
                              hipStream_t stream)
{
    const float* x   = (const float*)d_in[0];
    const float* w1  = (const float*)d_in[1];
    const float* w2  = (const float*)d_in[2];
    const float* wid = (const float*)d_in[3];
    float* out = (float*)d_out;

    char* ws = (char*)d_ws;
    ushort_t* xT  = (ushort_t*)ws;                         // 53,231,616 B (+4K pad)
    ushort_t* o1T = (ushort_t*)(ws + 53235712);            // 29,491,200 B (+4K pad)
    ushort_t* wT1 = (ushort_t*)(ws + 82731008);            //    589,824 B
    ushort_t* wT2 = (ushort_t*)(ws + 83320832);            //  1,245,184 B
    uint_t*   hfA = (uint_t*)  (ws + 88498176);            //      8,192 B
    uint_t*   hfB = (uint_t*)  (ws + 88506368);            //      8,192 B
    uint_t*   cnt = (uint_t*)  (ws + 88514560);            //          8 B

    prep<<<dim3(139, 64), 256, 0, stream>>>((uint_t*)xT, (uint_t*)o1T,
                                            x, w1, w2, wid, wT1, wT2,
                                            hfA, hfB, cnt, xT);

    conv1_mfma<<<448, 256, 0, stream>>>(xT, wT1, o1T, hfA, &cnt[0],
                                        out + OUT_ELEMS);
    conv2_mfma<<<dim3(256, 2), 256, 0, stream>>>(o1T, xT, wT2, out, hfB,
                                                 &cnt[1], out + OUT_ELEMS + 99);
}

// Round 11
// 334.251 us; speedup vs baseline: 1.3992x; 1.3992x over previous
//
#include <hip/hip_runtime.h>

typedef unsigned short ushort_t;
typedef unsigned int uint_t;

using short8 = __attribute__((ext_vector_type(8))) short;
using f32x4  = __attribute__((ext_vector_type(4))) float;

#define N_BATCH   64
#define C_MID     256
#define H_OUT     28
#define W_OUT     28
#define SPATIAL   (H_OUT*W_OUT)
#define OUT_ELEMS (N_BATCH*C_MID*SPATIAL)   // 12,845,056

// histogram: 2048 bins over [-16,16), width 1/64
#define NBINS 2048
#define BIN_LO (-16.0f)
#define BIN_INV 64.0f
#define BIN_W  0.015625f

// padded channels-last geometry (u16 element units)
#define XT_ROW   (57*128)        // 7296
#define XT_IMG   (57*57*128)     // 415872
#define O1_ROW   (30*256)        // 7680
#define O1_IMG   (30*30*256)     // 230400

// counted waits + raw barrier (memory clobber pins LDS reads/writes ordering)
#define WAITVM(n) asm volatile("s_waitcnt vmcnt(" #n ")" ::: "memory")
#define BARRIER() asm volatile("s_barrier" ::: "memory")

__device__ __forceinline__ ushort_t f2bf(float f) {
    uint_t u = __float_as_uint(f);
    u += 0x7FFFu + ((u >> 16) & 1u);
    return (ushort_t)(u >> 16);
}

__device__ __forceinline__ void gll16(const ushort_t* g, void* l) {
    __builtin_amdgcn_global_load_lds(
        (const __attribute__((address_space(1))) unsigned int*)g,
        (__attribute__((address_space(3))) unsigned int*)l, 16, 0, 0);
}

// ---------------------------------------------------------------------------
// prep: merged zwtrans + xtrans.
//   bxx <  87 : zero borders of xT/o1T
//   87..124   : weight transform + zero hf
//   125..138  : xtrans (NCHW f32 -> padded channels-last bf16), g = bxx-125
// ---------------------------------------------------------------------------
__global__ __launch_bounds__(256) void prep(
    uint_t* __restrict__ xT32, uint_t* __restrict__ o1T32,
    const float* __restrict__ x, const float* __restrict__ w1,
    const float* __restrict__ w2, const float* __restrict__ wid,
    ushort_t* __restrict__ wT1, ushort_t* __restrict__ wT2,
    uint_t* __restrict__ hfA, uint_t* __restrict__ hfB,
    ushort_t* __restrict__ xT)
{
    __shared__ ushort_t t[224 * 130];
    const int bxx = blockIdx.x, y = blockIdx.y, tid = threadIdx.x;
    if (bxx < 87) {
        int i = bxx * 256 + tid;
        int n = y;
        if (i >= 22080) return;
        if (i < 7232) {
            uint_t* base = xT32 + (size_t)n * (XT_IMG / 2);
            if (i < 3648) base[i] = 0;                              // row 0
            else { int j = i - 3648; int r = (j >> 6) + 1;          // col 0
                   base[r * (XT_ROW / 2) + (j & 63)] = 0; }
        } else {
            int k = i - 7232;
            uint_t* base = o1T32 + (size_t)n * (O1_IMG / 2);
            if (k < 3840) base[k] = 0;                              // row 0
            else if (k < 7680) base[29 * (O1_ROW / 2) + (k - 3840)] = 0;
            else if (k < 11264) { int j = k - 7680; int r = (j >> 7) + 1;
                   base[r * (O1_ROW / 2) + (j & 127)] = 0; }        // col 0
            else { int j = k - 11264; int r = (j >> 7) + 1;
                   base[r * (O1_ROW / 2) + 29 * 128 + (j & 127)] = 0; }
        }
    } else if (bxx < 125) {
        int idx = ((bxx - 87) * 64 + y) * 256 + tid;   // 0..622591
        if (idx < 2048)      hfA[idx] = 0;
        else if (idx < 4096) hfB[idx - 2048] = 0;
        if (idx < 256 * 1152) {
            int co = idx / 1152, k = idx % 1152;
            int g = k >> 7, ci = k & 127;
            wT1[idx] = f2bf(w1[(co * 128 + ci) * 9 + g]);
        }
        if (idx < 256 * 2432) {
            int co = idx / 2432, k = idx % 2432;
            float v;
            if (k < 2304) { int g = k >> 8, ci = k & 255; v = w2[(co * 256 + ci) * 9 + g]; }
            else          { v = wid[co * 128 + (k - 2304)]; }
            wT2[idx] = f2bf(v);
        }
    } else {
        const int g = bxx - 125, n = y;
        const float* xs = x + ((size_t)n * 128) * 3136 + g * 4 * 56;
        #pragma unroll
        for (int it = 0; it < 28; ++it) {
            int f = it * 256 + tid;      // 7168 = 128 ci x 56 float4
            int ci = f / 56, r4 = f % 56;
            float4 v = *(const float4*)(xs + ci * 3136 + r4 * 4);
            t[(r4 * 4 + 0) * 130 + ci] = f2bf(v.x);
            t[(r4 * 4 + 1) * 130 + ci] = f2bf(v.y);
            t[(r4 * 4 + 2) * 130 + ci] = f2bf(v.z);
            t[(r4 * 4 + 3) * 130 + ci] = f2bf(v.w);
        }
        __syncthreads();
        ushort_t* xo = xT + (size_t)n * XT_IMG + (g * 4 + 1) * XT_ROW + 128;
        for (int it = 0; it < 56; ++it) {
            int f = it * 256 + tid;
            int pos = f >> 6, c2 = f & 63;
            int r = pos / 56, iw = pos % 56;
            uint_t v = *(const uint_t*)&t[pos * 130 + c2 * 2];
            *(uint_t*)(xo + r * XT_ROW + iw * 128 + c2 * 2) = v;
        }
    }
}

// ---------------------------------------------------------------------------
// conv1 (R1/R5/R8 inner loop, best measured). A staging wave-private
// (counted vmcnt, no per-tap barrier); 2 barriers per ci-chunk for the
// shared B patch. Epilogue: LDS hist -> hf via atomicAdd (NO fence — the
// kernel boundary publishes to select_k; R10 showed per-block fences
// trigger L2 writebacks that wreck the main loop).
// ---------------------------------------------------------------------------
__global__ __launch_bounds__(256, 2) void conv1_mfma(
    const ushort_t* __restrict__ xT, const ushort_t* __restrict__ wT1,
    ushort_t* __restrict__ o1T, uint_t* __restrict__ hf)
{
    const int bx = blockIdx.x;           // n*7 + rg
    const int tid = threadIdx.x;
    const int wv = tid >> 6, lane = tid & 63;
    const int ln = lane & 15, quad = lane >> 4;
    const int n = bx / 7, rg = bx % 7, r0 = rg * 4;

    __shared__ short8 Ald[2 * 1024];     // 32 KB  [buf][k8 4][co 256]
    __shared__ short8 Bp[2304];          // 36 KB  [k8 4][dr 9][j 57] (513/plane)

    f32x4 acc[4][7];
    #pragma unroll
    for (int a = 0; a < 4; ++a)
        #pragma unroll
        for (int b = 0; b < 7; ++b) acc[a][b] = (f32x4){0.f, 0.f, 0.f, 0.f};

    int drb[7], cl0[7];
    #pragma unroll
    for (int b = 0; b < 7; ++b) {
        int p = b * 16 + ln;
        drb[b] = 2 * (p / 28);           // + kh at use
        cl0[b] = p % 28;
    }

    uint_t poff[9];
    #pragma unroll
    for (int i = 0; i < 9; ++i) {
        int slot = (i * 4 + wv) * 64 + lane;
        int s2 = min(slot, 2051);
        int k8 = s2 / 513;
        int rem = s2 - k8 * 513;
        int dr = rem / 57, j = rem - dr * 57;
        int col = (j < 29) ? (2 * j) : (2 * (j - 29) + 1);
        poff[i] = (uint_t)((2 * r0 + dr) * XT_ROW + col * 128 + k8 * 8);
    }
    const uint_t aoff = (uint_t)((wv * 64 + lane) * 1152);

    const ushort_t* xTimg = xT + (size_t)n * XT_IMG;

    auto stageA = [&](int tap, int c, int buf) {
        #pragma unroll
        for (int jj = 0; jj < 4; ++jj)
            gll16(wT1 + aoff + jj * 8 + tap * 128 + c * 32,
                  (char*)Ald + buf * 16384 + (jj * 256 + wv * 64) * 16);
    };

    for (int c = 0; c < 4; ++c) {
        BARRIER();                       // all waves done reading Bp (prev chunk)
        #pragma unroll
        for (int i = 0; i < 9; ++i)
            gll16(xTimg + poff[i] + c * 32, (char*)Bp + ((i * 4 + wv) * 64) * 16);
        if (c == 0) stageA(0, 0, 0);
        WAITVM(0);                       // own B (+pending A) arrived
        BARRIER();                       // everyone's B arrived

        #pragma unroll
        for (int t = 0; t < 9; ++t) {
            const int st = c * 9 + t;
            const int buf = st & 1;
            if (t < 8)      stageA(t + 1, c, buf ^ 1);
            else if (c < 3) stageA(0, c + 1, buf ^ 1);
            if (c == 3 && t == 8) { WAITVM(0); } else { WAITVM(4); }
            const int kh = t / 3, kw = t - kh * 3;
            short8 af[4], bf[7];
            #pragma unroll
            for (int a = 0; a < 4; ++a)
                af[a] = Ald[buf * 1024 + quad * 256 + wv * 64 + a * 16 + ln];
            #pragma unroll
            for (int b = 0; b < 7; ++b) {
                int dr = drb[b] + kh;
                int j = (kw == 1) ? (29 + cl0[b]) : (cl0[b] + (kw >> 1));
                bf[b] = Bp[quad * 513 + dr * 57 + j];
            }
            __builtin_amdgcn_s_setprio(1);
            #pragma unroll
            for (int a = 0; a < 4; ++a)
                #pragma unroll
                for (int b = 0; b < 7; ++b)
                    acc[a][b] = __builtin_amdgcn_mfma_f32_16x16x32_bf16(
                        af[a], bf[b], acc[a][b], 0, 0, 0);
            __builtin_amdgcn_s_setprio(0);
        }
    }

    // epilogue: hist overlaid on Ald; clamp -> bf16 o1T (padded channels-last)
    __syncthreads();
    uint_t* hist = (uint_t*)Ald;
    for (int i = tid; i < NBINS; i += 256) hist[i] = 0;
    __syncthreads();

    ushort_t* oimg = o1T + (size_t)n * O1_IMG;
    #pragma unroll
    for (int a = 0; a < 4; ++a) {
        int co = wv * 64 + a * 16 + quad * 4;
        #pragma unroll
        for (int b = 0; b < 7; ++b) {
            int p = b * 16 + ln;
            int h = r0 + p / 28, w = p % 28;
            ushort_t pk[4];
            #pragma unroll
            for (int r = 0; r < 4; ++r) {
                float v = acc[a][b][r];
                int bin = (int)((v - BIN_LO) * BIN_INV);
                bin = min(max(bin, 0), NBINS - 1);
                atomicAdd(&hist[bin], 1u);
                pk[r] = f2bf(fminf(fmaxf(v, 0.f), 1.f));
            }
            uint2 u; u.x = (uint_t)pk[0] | ((uint_t)pk[1] << 16);
            u.y = (uint_t)pk[2] | ((uint_t)pk[3] << 16);
            *(uint2*)(oimg + ((h + 1) * 30 + (w + 1)) * 256 + co) = u;
        }
    }

    __syncthreads();
    for (int i = tid; i < NBINS; i += 256) {
        uint_t v = hist[i];
        if (v) atomicAdd(&hf[i], v);
    }
}

// ---------------------------------------------------------------------------
// conv2 + fused identity (R9 tap-paired pipeline, equal-best measured).
// Epilogue: LDS hist -> hf via atomicAdd (no fence).
// ---------------------------------------------------------------------------
__global__ __launch_bounds__(256, 2) void conv2_mfma(
    const ushort_t* __restrict__ o1T, const ushort_t* __restrict__ xT,
    const ushort_t* __restrict__ wT2, float* __restrict__ fout,
    uint_t* __restrict__ hf)
{
    const int bx = blockIdx.x;           // n*4 + rg
    const int by = blockIdx.y;
    const int tid = threadIdx.x;
    const int wv = tid >> 6, lane = tid & 63;
    const int ln = lane & 15, quad = lane >> 4;
    const int n = bx >> 2, rg = bx & 3, r0 = rg * 8;
    const int coh = wv & 1;
    const int pt  = wv >> 1;

    __shared__ short8 Ad[4 * 512];       // 32 KB [slot 4][k8 4][co 128]
    __shared__ short8 Bp[2 * 1280];      // 40 KB [buf 2][ci8 4][dr 10][col 32]

    f32x4 acc[4][7];
    #pragma unroll
    for (int a = 0; a < 4; ++a)
        #pragma unroll
        for (int b = 0; b < 7; ++b) acc[a][b] = (f32x4){0.f, 0.f, 0.f, 0.f};

    int prb[7], cl0[7], hlog[7];
    #pragma unroll
    for (int b = 0; b < 7; ++b) {
        int p = b * 16 + ln;
        int h = r0 + pt * 4 + p / 28;
        hlog[b] = h;
        prb[b] = (min(h, 27) - r0) * 32;
        cl0[b] = p % 28;
    }

    uint_t po[5];
    #pragma unroll
    for (int jj = 0; jj < 5; ++jj) {
        int f = (wv * 5 + jj) * 64 + lane;
        int ci8 = f / 320, rem = f % 320;
        int dr = rem >> 5, cl = rem & 31;
        po[jj] = (uint_t)(min(r0 + dr, 29) * O1_ROW + cl * 256 + ci8 * 8);
    }
    uint_t io[4];
    #pragma unroll
    for (int jj = 0; jj < 4; ++jj) {
        int i2 = min(wv * 4 + jj, 13);
        int slot = i2 * 64 + lane;
        int ci8 = slot / 224, pos = slot % 224;
        int h = min(r0 + pos / 28, 27), w = pos % 28;
        io[jj] = (uint_t)(((2 * h + 1) * 57 + (2 * w + 1)) * 128 + ci8 * 8);
    }

    const ushort_t* o1img = o1T + (size_t)n * O1_IMG;
    const ushort_t* xTimg = xT + (size_t)n * XT_IMG;
    const ushort_t* Ab0 = wT2 + (size_t)(by * 128 + lane) * 2432 + wv * 8;
    const ushort_t* Ab1 = Ab0 + (size_t)64 * 2432;

    auto stageA = [&](int k0, int slot) {          // 2 insts/wave = 8 KB/slot
        gll16(Ab0 + k0, (char*)Ad + slot * 8192 + wv * 2048);
        gll16(Ab1 + k0, (char*)Ad + slot * 8192 + wv * 2048 + 1024);
    };
    auto stageB = [&](int hb, int coff) {          // 5 insts/wave = 20 KB total
        #pragma unroll
        for (int jj = 0; jj < 5; ++jj)
            gll16(o1img + po[jj] + coff, (char*)Bp + hb * 20480 + (wv * 5 + jj) * 1024);
    };
    auto stageI = [&](int ib, int idh) {           // 4 insts/wave
        #pragma unroll
        for (int jj = 0; jj < 4; ++jj) {
            int i2 = min(wv * 4 + jj, 13);
            gll16(xTimg + io[jj] + idh * 32, (char*)Bp + ib * 20480 + i2 * 1024);
        }
    };

    // one tap's compute: af from A slot SL, bf from B buf HD at tap T
#define STEP_MFMA(SL, HD, T) do {                                             \
    const int kh_ = (T) / 3, kw_ = (T) % 3;                                   \
    short8 af_[4], bf_[7];                                                    \
    _Pragma("unroll")                                                         \
    for (int a_ = 0; a_ < 4; ++a_)                                            \
        af_[a_] = Ad[(SL) * 512 + quad * 128 + coh * 64 + a_ * 16 + ln];      \
    _Pragma("unroll")                                                         \
    for (int b_ = 0; b_ < 7; ++b_)                                            \
        bf_[b_] = Bp[(HD) * 1280 + quad * 320 + prb[b_] +                     \
                     kh_ * 32 + cl0[b_] + kw_];                               \
    __builtin_amdgcn_s_setprio(1);                                            \
    _Pragma("unroll")                                                         \
    for (int a_ = 0; a_ < 4; ++a_)                                            \
        _Pragma("unroll")                                                     \
        for (int b_ = 0; b_ < 7; ++b_)                                        \
            acc[a_][b_] = __builtin_amdgcn_mfma_f32_16x16x32_bf16(            \
                af_[a_], bf_[b_], acc[a_][b_], 0, 0, 0);                      \
    __builtin_amdgcn_s_setprio(0);                                            \
} while (0)

// one pair: steps s0 = hh*18 + 2Q, s0+1. All staging post-barrier.
#define PAIR(Q) do {                                                          \
    const int c0 = 2 * (Q), c1 = c0 + 1;                                      \
    const int t0_ = c0 % 9, t1_ = c1 % 9;                                     \
    const int hd0 = c0 / 9, hd1 = c1 / 9;                                     \
    WAITVM(0);                                                                \
    BARRIER();                                                                \
    {   /* stage A for steps s0+2, s0+3 */                                    \
        const int u0 = c0 + 2, u1 = c0 + 3;                                   \
        int k0_, k1_;                                                         \
        if (u0 < 18) k0_ = (u0 % 9) * 256 + (hh * 2 + u0 / 9) * 32;           \
        else k0_ = lastsup ? 2304                                             \
                           : ((u0 - 18) % 9) * 256 + (hh * 2 + 2) * 32;       \
        if (u1 < 18) k1_ = (u1 % 9) * 256 + (hh * 2 + u1 / 9) * 32;           \
        else k1_ = lastsup ? (2304 + (u1 - 18) * 32)                          \
                           : ((u1 - 18) % 9) * 256 + (hh * 2 + 2) * 32;       \
        stageA(k0_, (hh * 18 + u0) & 3);                                      \
        stageA(k1_, (hh * 18 + u1) & 3);                                      \
    }                                                                         \
    if ((Q) == 0) {                       /* t(s1)==1, h = 2hh   */           \
        stageB(1, (hh * 2 + 1) * 32);                                         \
    } else if ((Q) == 5) {                /* t(s0)==1, h = 2hh+1 */           \
        if (!lastsup) stageB(0, (hh * 2 + 2) * 32);                           \
        else          stageI(0, 0);                                           \
    }                                                                         \
    STEP_MFMA((hh * 18 + c0) & 3, hd0, t0_);                                  \
    STEP_MFMA((hh * 18 + c1) & 3, hd1, t1_);                                  \
} while (0)

    // prologue: A(0), A(1), B(chunk 0); retired+published by pair 0
    stageA(0, 0);
    stageA(256, 1);
    stageB(0, 0);

    for (int hh = 0; hh < 4; ++hh) {     // 2 chunks (18 steps, 9 pairs) each
        const bool lastsup = (hh == 3);
        PAIR(0); PAIR(1); PAIR(2); PAIR(3); PAIR(4);
        PAIR(5); PAIR(6); PAIR(7); PAIR(8);
    }
#undef PAIR

    // identity: 4 singleton steps (lead-1 pattern). Step 72+idh: A slot
    // idh (A72,A73 staged at main pair 35; A74,A75 staged at idh 0,1).
    #pragma unroll
    for (int idh = 0; idh < 4; ++idh) {
        WAITVM(0);
        BARRIER();
        if (idh < 2) stageA(2304 + (idh + 2) * 32, idh + 2);
        if (idh < 3) stageI((idh + 1) & 1, idh + 1);
        short8 af[4], bf[7];
        #pragma unroll
        for (int a = 0; a < 4; ++a)
            af[a] = Ad[idh * 512 + quad * 128 + coh * 64 + a * 16 + ln];
        #pragma unroll
        for (int b = 0; b < 7; ++b)
            bf[b] = Bp[(idh & 1) * 1280 + quad * 224 + pt * 112 + b * 16 + ln];
        __builtin_amdgcn_s_setprio(1);
        #pragma unroll
        for (int a = 0; a < 4; ++a)
            #pragma unroll
            for (int b = 0; b < 7; ++b)
                acc[a][b] = __builtin_amdgcn_mfma_f32_16x16x32_bf16(
                    af[a], bf[b], acc[a][b], 0, 0, 0);
        __builtin_amdgcn_s_setprio(0);
    }
#undef STEP_MFMA

    // epilogue: hist overlaid on Ad; clamp -> f32 out (NCHW)
    __syncthreads();
    uint_t* hist = (uint_t*)Ad;
    for (int i = tid; i < NBINS; i += 256) hist[i] = 0;
    __syncthreads();

    #pragma unroll
    for (int a = 0; a < 4; ++a) {
        int co = by * 128 + coh * 64 + a * 16 + quad * 4;
        #pragma unroll
        for (int b = 0; b < 7; ++b) {
            if (hlog[b] <= 27) {
                #pragma unroll
                for (int r = 0; r < 4; ++r) {
                    float v = acc[a][b][r];
                    int bin = (int)((v - BIN_LO) * BIN_INV);
                    bin = min(max(bin, 0), NBINS - 1);
                    atomicAdd(&hist[bin], 1u);
                    fout[((size_t)(n * 256 + co + r)) * SPATIAL +
                         hlog[b] * 28 + cl0[b]] = fminf(fmaxf(v, 0.f), 1.f);
                }
            }
        }
    }

    __syncthreads();
    for (int i = tid; i < NBINS; i += 256) {
        uint_t v = hist[i];
        if (v) atomicAdd(&hf[i], v);
    }
}

// ---------------------------------------------------------------------------
// Select 99 percentile values from each 2048-bin histogram (both in one
// launch: blockIdx.x picks histogram A/B). Reads hf across the kernel
// boundary (stream-ordered visibility; no fences needed).
// ---------------------------------------------------------------------------
__global__ __launch_bounds__(1024) void select_k(
    const uint_t* __restrict__ hfA, const uint_t* __restrict__ hfB,
    float* __restrict__ outp)
{
    const uint_t* hf = blockIdx.x ? hfB : hfA;
    float* op = outp + blockIdx.x * 99;
    __shared__ uint_t cs[1024];
    int t = threadIdx.x;
    uint_t s = hf[2 * t] + hf[2 * t + 1];
    cs[t] = s;
    __syncthreads();
    for (int d = 1; d < 1024; d <<= 1) {
        uint_t v = (t >= d) ? cs[t - d] : 0;
        __syncthreads();
        cs[t] += v;
        __syncthreads();
    }
    if (t >= 1 && t <= 99) {
        long long k = 1 + (long long)llrint(0.01 * (double)t * (double)(OUT_ELEMS - 1));
        int lo = 0, hi = 1023;
        while (lo < hi) { int mid = (lo + hi) >> 1; if ((long long)cs[mid] < k) lo = mid + 1; else hi = mid; }
        long long cum = (lo == 0) ? 0 : (long long)cs[lo - 1];
        int b = lo * 2;
        while (cum + (long long)hf[b] < k) { cum += hf[b]; ++b; }
        op[t - 1] = BIN_LO + ((float)b + 0.5f) * BIN_W;
    }
}

// ---------------------------------------------------------------------------
extern "C" void kernel_launch(void* const* d_in, const int* in_sizes, int n_in,
                              void* d_out, int out_size, void* d_ws, size_t ws_size,
                              hipStream_t stream)
{
    const float* x   = (const float*)d_in[0];
    const float* w1  = (const float*)d_in[1];
    const float* w2  = (const float*)d_in[2];
    const float* wid = (const float*)d_in[3];
    float* out = (float*)d_out;

    char* ws = (char*)d_ws;
    ushort_t* xT  = (ushort_t*)ws;                         // 53,231,616 B (+4K pad)
    ushort_t* o1T = (ushort_t*)(ws + 53235712);            // 29,491,200 B (+4K pad)
    ushort_t* wT1 = (ushort_t*)(ws + 82731008);            //    589,824 B
    ushort_t* wT2 = (ushort_t*)(ws + 83320832);            //  1,245,184 B
    uint_t*   hfA = (uint_t*)  (ws + 88498176);            //      8,192 B
    uint_t*   hfB = (uint_t*)  (ws + 88506368);            //      8,192 B

    prep<<<dim3(139, 64), 256, 0, stream>>>((uint_t*)xT, (uint_t*)o1T,
                                            x, w1, w2, wid, wT1, wT2,
                                            hfA, hfB, xT);

    conv1_mfma<<<448, 256, 0, stream>>>(xT, wT1, o1T, hfA);
    conv2_mfma<<<dim3(256, 2), 256, 0, stream>>>(o1T, xT, wT2, out, hfB);

    select_k<<<2, 1024, 0, stream>>>(hfA, hfB, out + OUT_ELEMS);
}

// Round 12
// 334.128 us; speedup vs baseline: 1.3997x; 1.0004x over previous
//
#include <hip/hip_runtime.h>

typedef unsigned short ushort_t;
typedef unsigned int uint_t;

using short8 = __attribute__((ext_vector_type(8))) short;
using f32x4  = __attribute__((ext_vector_type(4))) float;

#define N_BATCH   64
#define C_MID     256
#define H_OUT     28
#define W_OUT     28
#define SPATIAL   (H_OUT*W_OUT)
#define OUT_ELEMS (N_BATCH*C_MID*SPATIAL)   // 12,845,056

// histogram: 2048 bins over [-16,16), width 1/64
#define NBINS 2048
#define HSTRIDE 2056            // per-wave hist stride (u32): +8 = 8-bank skew
#define BIN_LO (-16.0f)
#define BIN_INV 64.0f
#define BIN_W  0.015625f

// padded channels-last geometry (u16 element units)
#define XT_ROW   (57*128)        // 7296
#define XT_IMG   (57*57*128)     // 415872
#define O1_ROW   (30*256)        // 7680
#define O1_IMG   (30*30*256)     // 230400

// counted waits + raw barrier (memory clobber pins LDS reads/writes ordering)
#define WAITVM(n) asm volatile("s_waitcnt vmcnt(" #n ")" ::: "memory")
#define BARRIER() asm volatile("s_barrier" ::: "memory")

__device__ __forceinline__ ushort_t f2bf(float f) {
    uint_t u = __float_as_uint(f);
    u += 0x7FFFu + ((u >> 16) & 1u);
    return (ushort_t)(u >> 16);
}

__device__ __forceinline__ void gll16(const ushort_t* g, void* l) {
    __builtin_amdgcn_global_load_lds(
        (const __attribute__((address_space(1))) unsigned int*)g,
        (__attribute__((address_space(3))) unsigned int*)l, 16, 0, 0);
}

// ---------------------------------------------------------------------------
// prep: merged zwtrans + xtrans.
//   bxx <  87 : zero borders of xT/o1T
//   87..124   : weight transform + zero hf
//   125..138  : xtrans (NCHW f32 -> padded channels-last bf16), g = bxx-125
// ---------------------------------------------------------------------------
__global__ __launch_bounds__(256) void prep(
    uint_t* __restrict__ xT32, uint_t* __restrict__ o1T32,
    const float* __restrict__ x, const float* __restrict__ w1,
    const float* __restrict__ w2, const float* __restrict__ wid,
    ushort_t* __restrict__ wT1, ushort_t* __restrict__ wT2,
    uint_t* __restrict__ hfA, uint_t* __restrict__ hfB,
    ushort_t* __restrict__ xT)
{
    __shared__ ushort_t t[224 * 130];
    const int bxx = blockIdx.x, y = blockIdx.y, tid = threadIdx.x;
    if (bxx < 87) {
        int i = bxx * 256 + tid;
        int n = y;
        if (i >= 22080) return;
        if (i < 7232) {
            uint_t* base = xT32 + (size_t)n * (XT_IMG / 2);
            if (i < 3648) base[i] = 0;                              // row 0
            else { int j = i - 3648; int r = (j >> 6) + 1;          // col 0
                   base[r * (XT_ROW / 2) + (j & 63)] = 0; }
        } else {
            int k = i - 7232;
            uint_t* base = o1T32 + (size_t)n * (O1_IMG / 2);
            if (k < 3840) base[k] = 0;                              // row 0
            else if (k < 7680) base[29 * (O1_ROW / 2) + (k - 3840)] = 0;
            else if (k < 11264) { int j = k - 7680; int r = (j >> 7) + 1;
                   base[r * (O1_ROW / 2) + (j & 127)] = 0; }        // col 0
            else { int j = k - 11264; int r = (j >> 7) + 1;
                   base[r * (O1_ROW / 2) + 29 * 128 + (j & 127)] = 0; }
        }
    } else if (bxx < 125) {
        int idx = ((bxx - 87) * 64 + y) * 256 + tid;   // 0..622591
        if (idx < 2048)      hfA[idx] = 0;
        else if (idx < 4096) hfB[idx - 2048] = 0;
        if (idx < 256 * 1152) {
            int co = idx / 1152, k = idx % 1152;
            int g = k >> 7, ci = k & 127;
            wT1[idx] = f2bf(w1[(co * 128 + ci) * 9 + g]);
        }
        if (idx < 256 * 2432) {
            int co = idx / 2432, k = idx % 2432;
            float v;
            if (k < 2304) { int g = k >> 8, ci = k & 255; v = w2[(co * 256 + ci) * 9 + g]; }
            else          { v = wid[co * 128 + (k - 2304)]; }
            wT2[idx] = f2bf(v);
        }
    } else {
        const int g = bxx - 125, n = y;
        const float* xs = x + ((size_t)n * 128) * 3136 + g * 4 * 56;
        #pragma unroll
        for (int it = 0; it < 28; ++it) {
            int f = it * 256 + tid;      // 7168 = 128 ci x 56 float4
            int ci = f / 56, r4 = f % 56;
            float4 v = *(const float4*)(xs + ci * 3136 + r4 * 4);
            t[(r4 * 4 + 0) * 130 + ci] = f2bf(v.x);
            t[(r4 * 4 + 1) * 130 + ci] = f2bf(v.y);
            t[(r4 * 4 + 2) * 130 + ci] = f2bf(v.z);
            t[(r4 * 4 + 3) * 130 + ci] = f2bf(v.w);
        }
        __syncthreads();
        ushort_t* xo = xT + (size_t)n * XT_IMG + (g * 4 + 1) * XT_ROW + 128;
        for (int it = 0; it < 56; ++it) {
            int f = it * 256 + tid;
            int pos = f >> 6, c2 = f & 63;
            int r = pos / 56, iw = pos % 56;
            uint_t v = *(const uint_t*)&t[pos * 130 + c2 * 2];
            *(uint_t*)(xo + r * XT_ROW + iw * 128 + c2 * 2) = v;
        }
    }
}

// ---------------------------------------------------------------------------
// conv1 (R1/R5/R8 inner loop, best measured). A staging wave-private
// (counted vmcnt, no per-tap barrier); 2 barriers per ci-chunk for the
// shared B patch. Epilogue: WAVE-PRIVATE bank-skewed LDS hists (on Bp,
// 4 x 2056 u32) merged into hf via one atomicAdd/bin (no fence).
// ---------------------------------------------------------------------------
__global__ __launch_bounds__(256, 2) void conv1_mfma(
    const ushort_t* __restrict__ xT, const ushort_t* __restrict__ wT1,
    ushort_t* __restrict__ o1T, uint_t* __restrict__ hf)
{
    const int bx = blockIdx.x;           // n*7 + rg
    const int tid = threadIdx.x;
    const int wv = tid >> 6, lane = tid & 63;
    const int ln = lane & 15, quad = lane >> 4;
    const int n = bx / 7, rg = bx % 7, r0 = rg * 4;

    __shared__ short8 Ald[2 * 1024];     // 32 KB  [buf][k8 4][co 256]
    __shared__ short8 Bp[2304];          // 36 KB  [k8 4][dr 9][j 57] (513/plane)

    f32x4 acc[4][7];
    #pragma unroll
    for (int a = 0; a < 4; ++a)
        #pragma unroll
        for (int b = 0; b < 7; ++b) acc[a][b] = (f32x4){0.f, 0.f, 0.f, 0.f};

    int drb[7], cl0[7];
    #pragma unroll
    for (int b = 0; b < 7; ++b) {
        int p = b * 16 + ln;
        drb[b] = 2 * (p / 28);           // + kh at use
        cl0[b] = p % 28;
    }

    uint_t poff[9];
    #pragma unroll
    for (int i = 0; i < 9; ++i) {
        int slot = (i * 4 + wv) * 64 + lane;
        int s2 = min(slot, 2051);
        int k8 = s2 / 513;
        int rem = s2 - k8 * 513;
        int dr = rem / 57, j = rem - dr * 57;
        int col = (j < 29) ? (2 * j) : (2 * (j - 29) + 1);
        poff[i] = (uint_t)((2 * r0 + dr) * XT_ROW + col * 128 + k8 * 8);
    }
    const uint_t aoff = (uint_t)((wv * 64 + lane) * 1152);

    const ushort_t* xTimg = xT + (size_t)n * XT_IMG;

    auto stageA = [&](int tap, int c, int buf) {
        #pragma unroll
        for (int jj = 0; jj < 4; ++jj)
            gll16(wT1 + aoff + jj * 8 + tap * 128 + c * 32,
                  (char*)Ald + buf * 16384 + (jj * 256 + wv * 64) * 16);
    };

    for (int c = 0; c < 4; ++c) {
        BARRIER();                       // all waves done reading Bp (prev chunk)
        #pragma unroll
        for (int i = 0; i < 9; ++i)
            gll16(xTimg + poff[i] + c * 32, (char*)Bp + ((i * 4 + wv) * 64) * 16);
        if (c == 0) stageA(0, 0, 0);
        WAITVM(0);                       // own B (+pending A) arrived
        BARRIER();                       // everyone's B arrived

        #pragma unroll
        for (int t = 0; t < 9; ++t) {
            const int st = c * 9 + t;
            const int buf = st & 1;
            if (t < 8)      stageA(t + 1, c, buf ^ 1);
            else if (c < 3) stageA(0, c + 1, buf ^ 1);
            if (c == 3 && t == 8) { WAITVM(0); } else { WAITVM(4); }
            const int kh = t / 3, kw = t - kh * 3;
            short8 af[4], bf[7];
            #pragma unroll
            for (int a = 0; a < 4; ++a)
                af[a] = Ald[buf * 1024 + quad * 256 + wv * 64 + a * 16 + ln];
            #pragma unroll
            for (int b = 0; b < 7; ++b) {
                int dr = drb[b] + kh;
                int j = (kw == 1) ? (29 + cl0[b]) : (cl0[b] + (kw >> 1));
                bf[b] = Bp[quad * 513 + dr * 57 + j];
            }
            __builtin_amdgcn_s_setprio(1);
            #pragma unroll
            for (int a = 0; a < 4; ++a)
                #pragma unroll
                for (int b = 0; b < 7; ++b)
                    acc[a][b] = __builtin_amdgcn_mfma_f32_16x16x32_bf16(
                        af[a], bf[b], acc[a][b], 0, 0, 0);
            __builtin_amdgcn_s_setprio(0);
        }
    }

    // epilogue: wave-private hists on Bp; clamp -> bf16 o1T (channels-last)
    __syncthreads();
    uint_t* histb = (uint_t*)Bp;         // 9216 u32 available, need 4*2056=8224
    for (int i = tid; i < 4 * HSTRIDE; i += 256) histb[i] = 0;
    __syncthreads();
    uint_t* hw = histb + wv * HSTRIDE;

    ushort_t* oimg = o1T + (size_t)n * O1_IMG;
    #pragma unroll
    for (int a = 0; a < 4; ++a) {
        int co = wv * 64 + a * 16 + quad * 4;
        #pragma unroll
        for (int b = 0; b < 7; ++b) {
            int p = b * 16 + ln;
            int h = r0 + p / 28, w = p % 28;
            ushort_t pk[4];
            #pragma unroll
            for (int r = 0; r < 4; ++r) {
                float v = acc[a][b][r];
                int bin = (int)((v - BIN_LO) * BIN_INV);
                bin = min(max(bin, 0), NBINS - 1);
                atomicAdd(&hw[bin], 1u);
                pk[r] = f2bf(fminf(fmaxf(v, 0.f), 1.f));
            }
            uint2 u; u.x = (uint_t)pk[0] | ((uint_t)pk[1] << 16);
            u.y = (uint_t)pk[2] | ((uint_t)pk[3] << 16);
            *(uint2*)(oimg + ((h + 1) * 30 + (w + 1)) * 256 + co) = u;
        }
    }

    __syncthreads();
    for (int i = tid; i < NBINS; i += 256) {
        uint_t v = histb[i] + histb[HSTRIDE + i] +
                   histb[2 * HSTRIDE + i] + histb[3 * HSTRIDE + i];
        if (v) atomicAdd(&hf[i], v);
    }
}

// ---------------------------------------------------------------------------
// conv2 + fused identity (R9 tap-paired pipeline, equal-best measured).
// Epilogue: wave-private bank-skewed LDS hists (on Bp) -> hf (no fence).
// ---------------------------------------------------------------------------
__global__ __launch_bounds__(256, 2) void conv2_mfma(
    const ushort_t* __restrict__ o1T, const ushort_t* __restrict__ xT,
    const ushort_t* __restrict__ wT2, float* __restrict__ fout,
    uint_t* __restrict__ hf)
{
    const int bx = blockIdx.x;           // n*4 + rg
    const int by = blockIdx.y;
    const int tid = threadIdx.x;
    const int wv = tid >> 6, lane = tid & 63;
    const int ln = lane & 15, quad = lane >> 4;
    const int n = bx >> 2, rg = bx & 3, r0 = rg * 8;
    const int coh = wv & 1;
    const int pt  = wv >> 1;

    __shared__ short8 Ad[4 * 512];       // 32 KB [slot 4][k8 4][co 128]
    __shared__ short8 Bp[2 * 1280];      // 40 KB [buf 2][ci8 4][dr 10][col 32]

    f32x4 acc[4][7];
    #pragma unroll
    for (int a = 0; a < 4; ++a)
        #pragma unroll
        for (int b = 0; b < 7; ++b) acc[a][b] = (f32x4){0.f, 0.f, 0.f, 0.f};

    int prb[7], cl0[7], hlog[7];
    #pragma unroll
    for (int b = 0; b < 7; ++b) {
        int p = b * 16 + ln;
        int h = r0 + pt * 4 + p / 28;
        hlog[b] = h;
        prb[b] = (min(h, 27) - r0) * 32;
        cl0[b] = p % 28;
    }

    uint_t po[5];
    #pragma unroll
    for (int jj = 0; jj < 5; ++jj) {
        int f = (wv * 5 + jj) * 64 + lane;
        int ci8 = f / 320, rem = f % 320;
        int dr = rem >> 5, cl = rem & 31;
        po[jj] = (uint_t)(min(r0 + dr, 29) * O1_ROW + cl * 256 + ci8 * 8);
    }
    uint_t io[4];
    #pragma unroll
    for (int jj = 0; jj < 4; ++jj) {
        int i2 = min(wv * 4 + jj, 13);
        int slot = i2 * 64 + lane;
        int ci8 = slot / 224, pos = slot % 224;
        int h = min(r0 + pos / 28, 27), w = pos % 28;
        io[jj] = (uint_t)(((2 * h + 1) * 57 + (2 * w + 1)) * 128 + ci8 * 8);
    }

    const ushort_t* o1img = o1T + (size_t)n * O1_IMG;
    const ushort_t* xTimg = xT + (size_t)n * XT_IMG;
    const ushort_t* Ab0 = wT2 + (size_t)(by * 128 + lane) * 2432 + wv * 8;
    const ushort_t* Ab1 = Ab0 + (size_t)64 * 2432;

    auto stageA = [&](int k0, int slot) {          // 2 insts/wave = 8 KB/slot
        gll16(Ab0 + k0, (char*)Ad + slot * 8192 + wv * 2048);
        gll16(Ab1 + k0, (char*)Ad + slot * 8192 + wv * 2048 + 1024);
    };
    auto stageB = [&](int hb, int coff) {          // 5 insts/wave = 20 KB total
        #pragma unroll
        for (int jj = 0; jj < 5; ++jj)
            gll16(o1img + po[jj] + coff, (char*)Bp + hb * 20480 + (wv * 5 + jj) * 1024);
    };
    auto stageI = [&](int ib, int idh) {           // 4 insts/wave
        #pragma unroll
        for (int jj = 0; jj < 4; ++jj) {
            int i2 = min(wv * 4 + jj, 13);
            gll16(xTimg + io[jj] + idh * 32, (char*)Bp + ib * 20480 + i2 * 1024);
        }
    };

    // one tap's compute: af from A slot SL, bf from B buf HD at tap T
#define STEP_MFMA(SL, HD, T) do {                                             \
    const int kh_ = (T) / 3, kw_ = (T) % 3;                                   \
    short8 af_[4], bf_[7];                                                    \
    _Pragma("unroll")                                                         \
    for (int a_ = 0; a_ < 4; ++a_)                                            \
        af_[a_] = Ad[(SL) * 512 + quad * 128 + coh * 64 + a_ * 16 + ln];      \
    _Pragma("unroll")                                                         \
    for (int b_ = 0; b_ < 7; ++b_)                                            \
        bf_[b_] = Bp[(HD) * 1280 + quad * 320 + prb[b_] +                     \
                     kh_ * 32 + cl0[b_] + kw_];                               \
    __builtin_amdgcn_s_setprio(1);                                            \
    _Pragma("unroll")                                                         \
    for (int a_ = 0; a_ < 4; ++a_)                                            \
        _Pragma("unroll")                                                     \
        for (int b_ = 0; b_ < 7; ++b_)                                        \
            acc[a_][b_] = __builtin_amdgcn_mfma_f32_16x16x32_bf16(            \
                af_[a_], bf_[b_], acc[a_][b_], 0, 0, 0);                      \
    __builtin_amdgcn_s_setprio(0);                                            \
} while (0)

// one pair: steps s0 = hh*18 + 2Q, s0+1. All staging post-barrier.
#define PAIR(Q) do {                                                          \
    const int c0 = 2 * (Q), c1 = c0 + 1;                                      \
    const int t0_ = c0 % 9, t1_ = c1 % 9;                                     \
    const int hd0 = c0 / 9, hd1 = c1 / 9;                                     \
    WAITVM(0);                                                                \
    BARRIER();                                                                \
    {   /* stage A for steps s0+2, s0+3 */                                    \
        const int u0 = c0 + 2, u1 = c0 + 3;                                   \
        int k0_, k1_;                                                         \
        if (u0 < 18) k0_ = (u0 % 9) * 256 + (hh * 2 + u0 / 9) * 32;           \
        else k0_ = lastsup ? 2304                                             \
                           : ((u0 - 18) % 9) * 256 + (hh * 2 + 2) * 32;       \
        if (u1 < 18) k1_ = (u1 % 9) * 256 + (hh * 2 + u1 / 9) * 32;           \
        else k1_ = lastsup ? (2304 + (u1 - 18) * 32)                          \
                           : ((u1 - 18) % 9) * 256 + (hh * 2 + 2) * 32;       \
        stageA(k0_, (hh * 18 + u0) & 3);                                      \
        stageA(k1_, (hh * 18 + u1) & 3);                                      \
    }                                                                         \
    if ((Q) == 0) {                       /* t(s1)==1, h = 2hh   */           \
        stageB(1, (hh * 2 + 1) * 32);                                         \
    } else if ((Q) == 5) {                /* t(s0)==1, h = 2hh+1 */           \
        if (!lastsup) stageB(0, (hh * 2 + 2) * 32);                           \
        else          stageI(0, 0);                                           \
    }                                                                         \
    STEP_MFMA((hh * 18 + c0) & 3, hd0, t0_);                                  \
    STEP_MFMA((hh * 18 + c1) & 3, hd1, t1_);                                  \
} while (0)

    // prologue: A(0), A(1), B(chunk 0); retired+published by pair 0
    stageA(0, 0);
    stageA(256, 1);
    stageB(0, 0);

    for (int hh = 0; hh < 4; ++hh) {     // 2 chunks (18 steps, 9 pairs) each
        const bool lastsup = (hh == 3);
        PAIR(0); PAIR(1); PAIR(2); PAIR(3); PAIR(4);
        PAIR(5); PAIR(6); PAIR(7); PAIR(8);
    }
#undef PAIR

    // identity: 4 singleton steps (lead-1 pattern). Step 72+idh: A slot
    // idh (A72,A73 staged at main pair 35; A74,A75 staged at idh 0,1).
    #pragma unroll
    for (int idh = 0; idh < 4; ++idh) {
        WAITVM(0);
        BARRIER();
        if (idh < 2) stageA(2304 + (idh + 2) * 32, idh + 2);
        if (idh < 3) stageI((idh + 1) & 1, idh + 1);
        short8 af[4], bf[7];
        #pragma unroll
        for (int a = 0; a < 4; ++a)
            af[a] = Ad[idh * 512 + quad * 128 + coh * 64 + a * 16 + ln];
        #pragma unroll
        for (int b = 0; b < 7; ++b)
            bf[b] = Bp[(idh & 1) * 1280 + quad * 224 + pt * 112 + b * 16 + ln];
        __builtin_amdgcn_s_setprio(1);
        #pragma unroll
        for (int a = 0; a < 4; ++a)
            #pragma unroll
            for (int b = 0; b < 7; ++b)
                acc[a][b] = __builtin_amdgcn_mfma_f32_16x16x32_bf16(
                    af[a], bf[b], acc[a][b], 0, 0, 0);
        __builtin_amdgcn_s_setprio(0);
    }
#undef STEP_MFMA

    // epilogue: wave-private hists on Bp; clamp -> f32 out (NCHW)
    __syncthreads();
    uint_t* histb = (uint_t*)Bp;         // 10240 u32 available, need 8224
    for (int i = tid; i < 4 * HSTRIDE; i += 256) histb[i] = 0;
    __syncthreads();
    uint_t* hw = histb + wv * HSTRIDE;

    #pragma unroll
    for (int a = 0; a < 4; ++a) {
        int co = by * 128 + coh * 64 + a * 16 + quad * 4;
        #pragma unroll
        for (int b = 0; b < 7; ++b) {
            if (hlog[b] <= 27) {
                #pragma unroll
                for (int r = 0; r < 4; ++r) {
                    float v = acc[a][b][r];
                    int bin = (int)((v - BIN_LO) * BIN_INV);
                    bin = min(max(bin, 0), NBINS - 1);
                    atomicAdd(&hw[bin], 1u);
                    fout[((size_t)(n * 256 + co + r)) * SPATIAL +
                         hlog[b] * 28 + cl0[b]] = fminf(fmaxf(v, 0.f), 1.f);
                }
            }
        }
    }

    __syncthreads();
    for (int i = tid; i < NBINS; i += 256) {
        uint_t v = histb[i] + histb[HSTRIDE + i] +
                   histb[2 * HSTRIDE + i] + histb[3 * HSTRIDE + i];
        if (v) atomicAdd(&hf[i], v);
    }
}

// ---------------------------------------------------------------------------
// Select 99 percentile values from each 2048-bin histogram (both in one
// launch: blockIdx.x picks histogram A/B). Reads hf across the kernel
// boundary (stream-ordered visibility; no fences needed).
// ---------------------------------------------------------------------------
__global__ __launch_bounds__(1024) void select_k(
    const uint_t* __restrict__ hfA, const uint_t* __restrict__ hfB,
    float* __restrict__ outp)
{
    const uint_t* hf = blockIdx.x ? hfB : hfA;
    float* op = outp + blockIdx.x * 99;
    __shared__ uint_t cs[1024];
    int t = threadIdx.x;
    uint_t s = hf[2 * t] + hf[2 * t + 1];
    cs[t] = s;
    __syncthreads();
    for (int d = 1; d < 1024; d <<= 1) {
        uint_t v = (t >= d) ? cs[t - d] : 0;
        __syncthreads();
        cs[t] += v;
        __syncthreads();
    }
    if (t >= 1 && t <= 99) {
        long long k = 1 + (long long)llrint(0.01 * (double)t * (double)(OUT_ELEMS - 1));
        int lo = 0, hi = 1023;
        while (lo < hi) { int mid = (lo + hi) >> 1; if ((long long)cs[mid] < k) lo = mid + 1; else hi = mid; }
        long long cum = (lo == 0) ? 0 : (long long)cs[lo - 1];
        int b = lo * 2;
        while (cum + (long long)hf[b] < k) { cum += hf[b]; ++b; }
        op[t - 1] = BIN_LO + ((float)b + 0.5f) * BIN_W;
    }
}

// ---------------------------------------------------------------------------
extern "C" void kernel_launch(void* const* d_in, const int* in_sizes, int n_in,
                              void* d_out, int out_size, void* d_ws, size_t ws_size,
                              hipStream_t stream)
{
    const float* x   = (const float*)d_in[0];
    const float* w1  = (const float*)d_in[1];
    const float* w2  = (const float*)d_in[2];
    const float* wid = (const float*)d_in[3];
    float* out = (float*)d_out;

    char* ws = (char*)d_ws;
    ushort_t* xT  = (ushort_t*)ws;                         // 53,231,616 B (+4K pad)
    ushort_t* o1T = (ushort_t*)(ws + 53235712);            // 29,491,200 B (+4K pad)
    ushort_t* wT1 = (ushort_t*)(ws + 82731008);            //    589,824 B
    ushort_t* wT2 = (ushort_t*)(ws + 83320832);            //  1,245,184 B
    uint_t*   hfA = (uint_t*)  (ws + 88498176);            //      8,192 B
    uint_t*   hfB = (uint_t*)  (ws + 88506368);            //      8,192 B

    prep<<<dim3(139, 64), 256, 0, stream>>>((uint_t*)xT, (uint_t*)o1T,
                                            x, w1, w2, wid, wT1, wT2,
                                            hfA, hfB, xT);

    conv1_mfma<<<448, 256, 0, stream>>>(xT, wT1, o1T, hfA);
    conv2_mfma<<<dim3(256, 2), 256, 0, stream>>>(o1T, xT, wT2, out, hfB);

    select_k<<<2, 1024, 0, stream>>>(hfA, hfB, out + OUT_ELEMS);
}